// Round 10
// baseline (297.877 us; speedup 1.0000x reference)
//
#include <hip/hip_runtime.h>
#include <hip/hip_cooperative_groups.h>
#include <math.h>

namespace cg = cooperative_groups;

// BEV deformable attention encoder, layer l = L-1 only.
// Round 10: cooperative single-kernel retry at 512 blocks (r9's 800 likely
// exceeded co-residency capacity: AGPRs add to the launch_bounds VGPR cap ->
// 3 blocks/CU -> 768 < 800 -> silent launch reject). Block-stride loops per
// phase; gj-invariant CPB B-fragments hoisted. Checked launch with
// deterministic fallback to the proven r8 4-kernel path.

#define NP 1600   // 40*40 query pixels
#define NJ 100    // 10*10 kv pixels

typedef _Float16 f16x8 __attribute__((ext_vector_type(8)));
typedef float  f32x4  __attribute__((ext_vector_type(4)));
typedef float  f32x2  __attribute__((ext_vector_type(2)));

template<int CTRL>
__device__ __forceinline__ float dpp_add(float x) {
  int y = __builtin_amdgcn_update_dpp(0, __builtin_bit_cast(int, x),
                                      CTRL, 0xf, 0xf, true);
  return x + __builtin_bit_cast(float, y);
}

// ============================ fused cooperative kernel ======================
__global__ __launch_bounds__(256, 4) void k_fused(
    const float* __restrict__ x,   const float* __restrict__ wq,
    const float* __restrict__ wdw, const float* __restrict__ bdw,
    const float* __restrict__ wo2,
    const float* __restrict__ wk,  const float* __restrict__ wvw,
    const float* __restrict__ w0,  const float* __restrict__ b0,
    const float* __restrict__ w1,  const float* __restrict__ b1v,
    const float* __restrict__ cw2, const float* __restrict__ b2,
    const float* __restrict__ wout, const float* __restrict__ bout,
    float* __restrict__ qt,  float* __restrict__ kws,
    float* __restrict__ vt,  float* __restrict__ bias_t,
    float* __restrict__ inner, float* __restrict__ out) {
  // LDS arena shared across phases:
  //  P1: psum[4][72] @0 | su @1152 | sv @1312 | a16 @1472 | c16 @7232
  //  P2: v_lds[100][68] @0 | s_lds[16][100] @27200 | q_lds[64][20] @33600
  __shared__ __align__(16) char smem[38720];
  cg::grid_group grid = cg::this_grid();
  int b = blockIdx.x;
  int t = threadIdx.x;
  int lane = t & 63;
  int wv_id = t >> 6;

  // ================= P0: qt[p][512], block-stride over pixels ===============
  {
    int ch = 2 * t;            // thread owns channels ch, ch+1
    int g = ch >> 6;
    for (int pp = b; pp < 1600; pp += 512) {
      float acc0 = 0.f, acc1 = 0.f;
#pragma unroll
      for (int ci = 0; ci < 32; ++ci) {
        float xv = x[(g * 32 + ci) * NP + pp];
        acc0 = fmaf(wq[(size_t)ch * 32 + ci], xv, acc0);
        acc1 = fmaf(wq[(size_t)(ch + 1) * 32 + ci], xv, acc1);
      }
      f32x2 o; o[0] = acc0; o[1] = acc1;
      *(f32x2*)(qt + (size_t)pp * 512 + ch) = o;
    }
  }
  grid.sync();

  // ================= P1: offset net + sample + k/v conv + CPB ===============
  {
    float (*psum)[72]   = (float(*)[72])smem;
    float* su_l         = (float*)(smem + 1152);
    float* sv_l         = (float*)(smem + 1312);
    _Float16 (*a16)[72] = (_Float16(*)[72])(smem + 1472);
    _Float16 (*c16)[72] = (_Float16(*)[72])(smem + 7232);
    int row = lane & 15;
    int kgrp = lane >> 4;
    // gj-invariant CPB constants (hoisted)
    f16x8 B[4][2];
#pragma unroll
    for (int ct = 0; ct < 4; ++ct)
#pragma unroll
      for (int s = 0; s < 2; ++s)
#pragma unroll
        for (int e = 0; e < 8; ++e)
          B[ct][s][e] = (_Float16)w1[(ct * 16 + row) * 64 + s * 32 + kgrp * 8 + e];
    float b1c[4], w2c[4];
#pragma unroll
    for (int ct = 0; ct < 4; ++ct) {
      b1c[ct] = b1v[ct * 16 + row];
      w2c[ct] = cw2[ct * 16 + row];
    }
    float bb = b2[0];
    f16x8 zero8 = {};

    for (int gj = b; gj < 800; gj += 512) {
      int g = gj / 100;
      int j = gj - g * 100;
      int oy = j / 10, ox = j - (j / 10) * 10;

      // dw-conv partials: wave handles taps wv_id*9..+8; lane = d
      {
        float acc = 0.f;
        const float* qrow = qt + g * 64 + lane;
#pragma unroll
        for (int tu = 0; tu < 9; ++tu) {
          int tt = wv_id * 9 + tu;
          int ky = tt / 6, kx = tt - (tt / 6) * 6;
          int iy = oy * 4 - 1 + ky;
          int ix = ox * 4 - 1 + kx;
          if (iy >= 0 && iy < 40 && ix >= 0 && ix < 40)
            acc = fmaf(wdw[lane * 36 + tt], qrow[(size_t)(iy * 40 + ix) * 512], acc);
        }
        psum[wv_id][lane] = acc;
      }
      __syncthreads();

      // wave 0: gelu -> pw -> tanh*4 -> grid -> sample -> k/v conv
      if (wv_id == 0) {
        float accd = psum[0][lane] + psum[1][lane] + psum[2][lane] + psum[3][lane]
                   + bdw[lane];
        float od = 0.5f * accd * (1.0f + erff(accd * 0.70710678118654752440f));
        float px = wo2[lane] * od, py = wo2[64 + lane] * od;
#pragma unroll
        for (int m = 1; m < 64; m <<= 1) {
          px += __shfl_xor(px, m);
          py += __shfl_xor(py, m);
        }
        float ax = tanhf(px) * 4.f;
        float ay = tanhf(py) * 4.f;
        float vx = (float)ox + ax;
        float vy = (float)oy + ay;
        float g0 = 2.f * vx / 9.f - 1.f;
        float g1 = 2.f * vy / 9.f - 1.f;
        if (lane < 40) {
          float qc = (float)lane * (2.f / 39.f) - 1.f;
          float u = qc - g0;
          float vv2 = qc - g1;
          su_l[lane] = copysignf(log1pf(fabsf(u)), u);
          sv_l[lane] = copysignf(log1pf(fabsf(vv2)), vv2);
        }
        float gx = ((g0 + 1.f) * 40.f - 1.f) * 0.5f;
        float gy = ((g1 + 1.f) * 40.f - 1.f) * 0.5f;
        float x0f = floorf(gx), y0f = floorf(gy);
        float wx = gx - x0f, wy = gy - y0f;
        bool mx0 = (x0f >= 0.f) && (x0f <= 39.f);
        bool mx1 = (x0f + 1.f >= 0.f) && (x0f + 1.f <= 39.f);
        bool my0 = (y0f >= 0.f) && (y0f <= 39.f);
        bool my1 = (y0f + 1.f >= 0.f) && (y0f + 1.f <= 39.f);
        int ix0 = (int)fminf(fmaxf(x0f, 0.f), 39.f);
        int ix1 = (int)fminf(fmaxf(x0f + 1.f, 0.f), 39.f);
        int iy0 = (int)fminf(fmaxf(y0f, 0.f), 39.f);
        int iy1 = (int)fminf(fmaxf(y0f + 1.f, 0.f), 39.f);
        float w00 = (1.f - wx) * (1.f - wy) * ((mx0 && my0) ? 1.f : 0.f);
        float w10 = wx * (1.f - wy) * ((mx1 && my0) ? 1.f : 0.f);
        float w01 = (1.f - wx) * wy * ((mx0 && my1) ? 1.f : 0.f);
        float w11 = wx * wy * ((mx1 && my1) ? 1.f : 0.f);
        int b00 = iy0 * 40 + ix0, b10 = iy0 * 40 + ix1;
        int b01 = iy1 * 40 + ix0, b11 = iy1 * 40 + ix1;
        float kvc = 0.f;
        if (lane < 32) {
          const float* xc = x + (g * 32 + lane) * NP;
          kvc = w00 * xc[b00] + w10 * xc[b10] + w01 * xc[b01] + w11 * xc[b11];
        }
        const float* wkr = wk + (g * 64 + lane) * 32;
        const float* wvr = wvw + (g * 64 + lane) * 32;
        float wkreg[32], wvreg[32];
#pragma unroll
        for (int q4 = 0; q4 < 8; ++q4) {
          f32x4 a = *(const f32x4*)(wkr + q4 * 4);
          f32x4 bq = *(const f32x4*)(wvr + q4 * 4);
#pragma unroll
          for (int e = 0; e < 4; ++e) { wkreg[q4 * 4 + e] = a[e]; wvreg[q4 * 4 + e] = bq[e]; }
        }
        float kacc = 0.f, vacc = 0.f;
#pragma unroll
        for (int c = 0; c < 32; ++c) {
          float kvb = __shfl(kvc, c);
          kacc = fmaf(wkreg[c], kvb, kacc);
          vacc = fmaf(wvreg[c], kvb, vacc);
        }
        kws[(g * 64 + lane) * 100 + j] = kacc;
        vt[(size_t)gj * 64 + lane] = vacc;     // transposed, coalesced
      }
      __syncthreads();

      // fp16 layer-1 tables (all waves)
      for (int idx = t; idx < 2560; idx += 256) {
        int xi = idx >> 6, kk = idx & 63;
        a16[xi][kk] = (_Float16)fmaf(w0[2 * kk], su_l[xi], b0[kk]);
        c16[xi][kk] = (_Float16)(w0[2 * kk + 1] * sv_l[xi]);
      }
      __syncthreads();

      // cpb MFMA: per-wave 25 tiles
      float* outp = bias_t + (size_t)gj * 1600;
      int it0 = wv_id * 25;
      int iy = wv_id * 10;
      int ix = row;
      for (int it = it0; it < it0 + 25; ++it) {
        f32x4 acc[4];
#pragma unroll
        for (int ct = 0; ct < 4; ++ct) {
          acc[ct][0] = 0.f; acc[ct][1] = 0.f; acc[ct][2] = 0.f; acc[ct][3] = 0.f;
        }
#pragma unroll
        for (int s = 0; s < 2; ++s) {
          f16x8 av = *(const f16x8*)&a16[ix][s * 32 + kgrp * 8];
          f16x8 cv = *(const f16x8*)&c16[iy][s * 32 + kgrp * 8];
          f16x8 A = __builtin_elementwise_max(av + cv, zero8);
#pragma unroll
          for (int ct = 0; ct < 4; ++ct)
            acc[ct] = __builtin_amdgcn_mfma_f32_16x16x32_f16(A, B[ct][s], acc[ct], 0, 0, 0);
        }
        float part[4];
#pragma unroll
        for (int ri = 0; ri < 4; ++ri) {
          float s2 = 0.f;
#pragma unroll
          for (int ct = 0; ct < 4; ++ct) {
            float val = acc[ct][ri] + b1c[ct];
            s2 = fmaf(w2c[ct], fmaxf(val, 0.f), s2);
          }
          part[ri] = s2;
        }
#pragma unroll
        for (int ri = 0; ri < 4; ++ri) {
          part[ri] = dpp_add<0xB1>(part[ri]);    // quad_perm [1,0,3,2]
          part[ri] = dpp_add<0x4E>(part[ri]);    // quad_perm [2,3,0,1]
          part[ri] = dpp_add<0x141>(part[ri]);   // row_half_mirror
          part[ri] = dpp_add<0x140>(part[ri]);   // row_mirror
        }
        if (row == 0) {
          f32x4 o;
          o[0] = part[0] + bb; o[1] = part[1] + bb;
          o[2] = part[2] + bb; o[3] = part[3] + bb;
          *(f32x4*)(outp + it * 16 + kgrp * 4) = o;
        }
        ix += 16;
        if (ix >= 40) { ix -= 40; ++iy; }
      }
      __syncthreads();   // protect LDS arena for next gj iteration
    }
  }
  grid.sync();

  // ================= P2: attention (q on the fly) ===========================
  {
    float (*v_lds)[68]  = (float(*)[68])smem;
    float (*s_lds)[100] = (float(*)[100])(smem + 27200);
    float (*q_lds)[20]  = (float(*)[20])(smem + 33600);
    for (int u = b; u < 800; u += 512) {
      int h = u / 100;
      int i0 = (u - h * 100) * 16;
      for (int idx = t; idx < 6400; idx += 256) {
        int j = idx >> 6, d = idx & 63;
        v_lds[j][d] = vt[(size_t)h * 6400 + idx];
      }
      // q-tile on the fly: thread (d = t&63, i4 = t>>6) -> 4 pixels
      {
        int d = t & 63;
        int i4 = t >> 6;
        f32x4 wr[8];
#pragma unroll
        for (int qq = 0; qq < 8; ++qq)
          wr[qq] = *(const f32x4*)(wq + (size_t)(h * 64 + d) * 32 + qq * 4);
#pragma unroll
        for (int ii = 0; ii < 4; ++ii) {
          int i = i4 * 4 + ii;
          float acc = 0.f;
#pragma unroll
          for (int ci = 0; ci < 32; ++ci)
            acc = fmaf(wr[ci >> 2][ci & 3], x[(h * 32 + ci) * NP + i0 + i], acc);
          q_lds[d][i] = acc;
        }
      }
      __syncthreads();
      if (t < 200) {
        int ib = (t / 25) * 2, jb = (t % 25) * 4;
        const float* kp = kws + h * 64 * 100 + jb;
        float a[2][4];
#pragma unroll
        for (int ii = 0; ii < 2; ++ii)
#pragma unroll
          for (int jj = 0; jj < 4; ++jj) a[ii][jj] = 0.f;
#pragma unroll 8
        for (int d = 0; d < 64; ++d) {
          f32x2 qv = *(const f32x2*)&q_lds[d][ib];
          f32x4 kv4 = *(const f32x4*)(kp + d * 100);
#pragma unroll
          for (int ii = 0; ii < 2; ++ii)
#pragma unroll
            for (int jj = 0; jj < 4; ++jj)
              a[ii][jj] = fmaf(qv[ii], kv4[jj], a[ii][jj]);
        }
        const float* bcol = bias_t + (size_t)h * 100 * 1600;
#pragma unroll
        for (int jj = 0; jj < 4; ++jj) {
          f32x2 bv = *(const f32x2*)(bcol + (size_t)(jb + jj) * 1600 + i0 + ib);
#pragma unroll
          for (int ii = 0; ii < 2; ++ii)
            s_lds[ib + ii][jb + jj] = fmaf(a[ii][jj], 0.125f, bv[ii]);
        }
      }
      __syncthreads();
      {
        int i = t >> 4, sub = t & 15;
        float m = -1e30f;
        for (int j = sub; j < 100; j += 16) m = fmaxf(m, s_lds[i][j]);
#pragma unroll
        for (int off = 1; off < 16; off <<= 1) m = fmaxf(m, __shfl_xor(m, off));
        float sum = 0.f;
        for (int j = sub; j < 100; j += 16) {
          float e = expf(s_lds[i][j] - m);
          s_lds[i][j] = e;
          sum += e;
        }
#pragma unroll
        for (int off = 1; off < 16; off <<= 1) sum += __shfl_xor(sum, off);
        float inv = 1.f / sum;
        for (int j = sub; j < 100; j += 16) s_lds[i][j] *= inv;
      }
      __syncthreads();
      {
        int i = t & 15, db = (t >> 4) * 4;
        float acc[4];
#pragma unroll
        for (int dd = 0; dd < 4; ++dd) acc[dd] = 0.f;
        for (int jc = 0; jc < 25; ++jc) {
          f32x4 sv = *(const f32x4*)&s_lds[i][jc * 4];
#pragma unroll
          for (int jj = 0; jj < 4; ++jj) {
            f32x4 vv = *(const f32x4*)&v_lds[jc * 4 + jj][db];
#pragma unroll
            for (int dd = 0; dd < 4; ++dd)
              acc[dd] = fmaf(sv[jj], vv[dd], acc[dd]);
          }
        }
#pragma unroll
        for (int dd = 0; dd < 4; ++dd)
          inner[(h * 64 + db + dd) * NP + i0 + i] = acc[dd];
      }
      __syncthreads();   // protect LDS arena for next u iteration
    }
  }
  grid.sync();

  // ================= P3: output projection ==================================
  {
    for (int u = b; u < 800; u += 512) {
      int oc = u & 31, pt = u >> 5;          // 32 o-chunks x 25 p-tiles
      int o0 = oc * 8 + (t >> 6) * 2;        // wave-uniform 2 couts
      int p = pt * 64 + (t & 63);
      const float* w0r = wout + (size_t)o0 * 512;
      float a0 = 0.f, a1 = 0.f;
#pragma unroll 8
      for (int c = 0; c < 512; ++c) {
        float xv = inner[c * NP + p];
        a0 = fmaf(w0r[c], xv, a0);
        a1 = fmaf(w0r[512 + c], xv, a1);
      }
      out[(o0 + 0) * NP + p] = a0 + bout[o0 + 0];
      out[(o0 + 1) * NP + p] = a1 + bout[o0 + 1];
    }
  }
}

// ============================ fallback: r8 kernels ==========================
__global__ __launch_bounds__(256) void k_conv1x1(
    const float* __restrict__ x, const float* __restrict__ w,
    float* __restrict__ out, float* __restrict__ out_t) {
  int b = blockIdx.x;
  int g = b / 40;
  int r = b - g * 40;
  int oc = r / 5;
  int p0 = (r - oc * 5) * 320;
  int co0 = g * 64 + oc * 8;
  const float* xg = x + g * 32 * NP;
  const float* wr = w + co0 * 32;
  for (int p = p0 + threadIdx.x; p < p0 + 320; p += 256) {
    float acc[8];
#pragma unroll
    for (int o = 0; o < 8; ++o) acc[o] = 0.f;
#pragma unroll
    for (int ci = 0; ci < 32; ++ci) {
      float xv = xg[ci * NP + p];
#pragma unroll
      for (int o = 0; o < 8; ++o) acc[o] = fmaf(wr[o * 32 + ci], xv, acc[o]);
    }
#pragma unroll
    for (int o = 0; o < 8; ++o) out[(co0 + o) * NP + p] = acc[o];
    f32x4 t0, t1;
    t0[0] = acc[0]; t0[1] = acc[1]; t0[2] = acc[2]; t0[3] = acc[3];
    t1[0] = acc[4]; t1[1] = acc[5]; t1[2] = acc[6]; t1[3] = acc[7];
    *(f32x4*)(out_t + (size_t)p * 512 + co0) = t0;
    *(f32x4*)(out_t + (size_t)p * 512 + co0 + 4) = t1;
  }
}

__global__ __launch_bounds__(256, 4) void k_off_cpb(
    const float* __restrict__ qt, const float* __restrict__ wdw,
    const float* __restrict__ bdw, const float* __restrict__ wo2,
    const float* __restrict__ x, const float* __restrict__ wk,
    const float* __restrict__ wv,
    const float* __restrict__ w0, const float* __restrict__ b0,
    const float* __restrict__ w1, const float* __restrict__ b1v,
    const float* __restrict__ cw2, const float* __restrict__ b2,
    float* __restrict__ kout, float* __restrict__ vout_t,
    float* __restrict__ bias_t) {
  __shared__ float psum[4][72];
  __shared__ float su_l[40];
  __shared__ float sv_l[40];
  __shared__ _Float16 a16[40][72];
  __shared__ _Float16 c16[40][72];
  int gj = blockIdx.x;
  int g = gj / 100;
  int j = gj - g * 100;
  int t = threadIdx.x;
  int lane = t & 63;
  int wv_id = t >> 6;
  int oy = j / 10, ox = j - (j / 10) * 10;
  {
    float acc = 0.f;
    const float* qrow = qt + g * 64 + lane;
#pragma unroll
    for (int tu = 0; tu < 9; ++tu) {
      int tt = wv_id * 9 + tu;
      int ky = tt / 6, kx = tt - (tt / 6) * 6;
      int iy = oy * 4 - 1 + ky;
      int ix = ox * 4 - 1 + kx;
      if (iy >= 0 && iy < 40 && ix >= 0 && ix < 40)
        acc = fmaf(wdw[lane * 36 + tt], qrow[(size_t)(iy * 40 + ix) * 512], acc);
    }
    psum[wv_id][lane] = acc;
  }
  __syncthreads();
  if (wv_id == 0) {
    float accd = psum[0][lane] + psum[1][lane] + psum[2][lane] + psum[3][lane]
               + bdw[lane];
    float od = 0.5f * accd * (1.0f + erff(accd * 0.70710678118654752440f));
    float px = wo2[lane] * od, py = wo2[64 + lane] * od;
#pragma unroll
    for (int m = 1; m < 64; m <<= 1) {
      px += __shfl_xor(px, m);
      py += __shfl_xor(py, m);
    }
    float ax = tanhf(px) * 4.f;
    float ay = tanhf(py) * 4.f;
    float vx = (float)ox + ax;
    float vy = (float)oy + ay;
    float g0 = 2.f * vx / 9.f - 1.f;
    float g1 = 2.f * vy / 9.f - 1.f;
    if (lane < 40) {
      float qc = (float)lane * (2.f / 39.f) - 1.f;
      float u = qc - g0;
      float vv2 = qc - g1;
      su_l[lane] = copysignf(log1pf(fabsf(u)), u);
      sv_l[lane] = copysignf(log1pf(fabsf(vv2)), vv2);
    }
    float gx = ((g0 + 1.f) * 40.f - 1.f) * 0.5f;
    float gy = ((g1 + 1.f) * 40.f - 1.f) * 0.5f;
    float x0f = floorf(gx), y0f = floorf(gy);
    float wx = gx - x0f, wy = gy - y0f;
    bool mx0 = (x0f >= 0.f) && (x0f <= 39.f);
    bool mx1 = (x0f + 1.f >= 0.f) && (x0f + 1.f <= 39.f);
    bool my0 = (y0f >= 0.f) && (y0f <= 39.f);
    bool my1 = (y0f + 1.f >= 0.f) && (y0f + 1.f <= 39.f);
    int ix0 = (int)fminf(fmaxf(x0f, 0.f), 39.f);
    int ix1 = (int)fminf(fmaxf(x0f + 1.f, 0.f), 39.f);
    int iy0 = (int)fminf(fmaxf(y0f, 0.f), 39.f);
    int iy1 = (int)fminf(fmaxf(y0f + 1.f, 0.f), 39.f);
    float w00 = (1.f - wx) * (1.f - wy) * ((mx0 && my0) ? 1.f : 0.f);
    float w10 = wx * (1.f - wy) * ((mx1 && my0) ? 1.f : 0.f);
    float w01 = (1.f - wx) * wy * ((mx0 && my1) ? 1.f : 0.f);
    float w11 = wx * wy * ((mx1 && my1) ? 1.f : 0.f);
    int b00 = iy0 * 40 + ix0, b10 = iy0 * 40 + ix1;
    int b01 = iy1 * 40 + ix0, b11 = iy1 * 40 + ix1;
    float kvc = 0.f;
    if (lane < 32) {
      const float* xc = x + (g * 32 + lane) * NP;
      kvc = w00 * xc[b00] + w10 * xc[b10] + w01 * xc[b01] + w11 * xc[b11];
    }
    const float* wkr = wk + (g * 64 + lane) * 32;
    const float* wvr = wv + (g * 64 + lane) * 32;
    float wkreg[32], wvreg[32];
#pragma unroll
    for (int q4 = 0; q4 < 8; ++q4) {
      f32x4 a = *(const f32x4*)(wkr + q4 * 4);
      f32x4 bq = *(const f32x4*)(wvr + q4 * 4);
#pragma unroll
      for (int e = 0; e < 4; ++e) { wkreg[q4 * 4 + e] = a[e]; wvreg[q4 * 4 + e] = bq[e]; }
    }
    float kacc = 0.f, vacc = 0.f;
#pragma unroll
    for (int c = 0; c < 32; ++c) {
      float kvb = __shfl(kvc, c);
      kacc = fmaf(wkreg[c], kvb, kacc);
      vacc = fmaf(wvreg[c], kvb, vacc);
    }
    kout[(g * 64 + lane) * 100 + j] = kacc;
    vout_t[(size_t)gj * 64 + lane] = vacc;
  }
  __syncthreads();
  for (int idx = t; idx < 2560; idx += 256) {
    int xi = idx >> 6, kk = idx & 63;
    a16[xi][kk] = (_Float16)fmaf(w0[2 * kk], su_l[xi], b0[kk]);
    c16[xi][kk] = (_Float16)(w0[2 * kk + 1] * sv_l[xi]);
  }
  int row = lane & 15;
  int kgrp = lane >> 4;
  f16x8 B[4][2];
#pragma unroll
  for (int ct = 0; ct < 4; ++ct)
#pragma unroll
    for (int s = 0; s < 2; ++s)
#pragma unroll
      for (int e = 0; e < 8; ++e)
        B[ct][s][e] = (_Float16)w1[(ct * 16 + row) * 64 + s * 32 + kgrp * 8 + e];
  float b1c[4], w2c[4];
#pragma unroll
  for (int ct = 0; ct < 4; ++ct) {
    b1c[ct] = b1v[ct * 16 + row];
    w2c[ct] = cw2[ct * 16 + row];
  }
  float bb = b2[0];
  float* outp = bias_t + (size_t)gj * 1600;
  __syncthreads();
  int it0 = wv_id * 25;
  int iy = wv_id * 10;
  int ix = row;
  f16x8 zero8 = {};
  for (int it = it0; it < it0 + 25; ++it) {
    f32x4 acc[4];
#pragma unroll
    for (int ct = 0; ct < 4; ++ct) {
      acc[ct][0] = 0.f; acc[ct][1] = 0.f; acc[ct][2] = 0.f; acc[ct][3] = 0.f;
    }
#pragma unroll
    for (int s = 0; s < 2; ++s) {
      f16x8 av = *(const f16x8*)&a16[ix][s * 32 + kgrp * 8];
      f16x8 cv = *(const f16x8*)&c16[iy][s * 32 + kgrp * 8];
      f16x8 A = __builtin_elementwise_max(av + cv, zero8);
#pragma unroll
      for (int ct = 0; ct < 4; ++ct)
        acc[ct] = __builtin_amdgcn_mfma_f32_16x16x32_f16(A, B[ct][s], acc[ct], 0, 0, 0);
    }
    float part[4];
#pragma unroll
    for (int ri = 0; ri < 4; ++ri) {
      float s2 = 0.f;
#pragma unroll
      for (int ct = 0; ct < 4; ++ct) {
        float val = acc[ct][ri] + b1c[ct];
        s2 = fmaf(w2c[ct], fmaxf(val, 0.f), s2);
      }
      part[ri] = s2;
    }
#pragma unroll
    for (int ri = 0; ri < 4; ++ri) {
      part[ri] = dpp_add<0xB1>(part[ri]);
      part[ri] = dpp_add<0x4E>(part[ri]);
      part[ri] = dpp_add<0x141>(part[ri]);
      part[ri] = dpp_add<0x140>(part[ri]);
    }
    if (row == 0) {
      f32x4 o;
      o[0] = part[0] + bb; o[1] = part[1] + bb;
      o[2] = part[2] + bb; o[3] = part[3] + bb;
      *(f32x4*)(outp + it * 16 + kgrp * 4) = o;
    }
    ix += 16;
    if (ix >= 40) { ix -= 40; ++iy; }
  }
}

__global__ __launch_bounds__(256) void k_attn(
    const float* __restrict__ q, const float* __restrict__ k,
    const float* __restrict__ v_t, const float* __restrict__ bias_t,
    float* __restrict__ inner) {
  __shared__ float v_lds[100][68];
  __shared__ float s_lds[16][100];
  int h = blockIdx.x / 100;
  int i0 = (blockIdx.x - h * 100) * 16;
  int t = threadIdx.x;
  for (int idx = t; idx < 6400; idx += 256) {
    int j = idx >> 6, d = idx & 63;
    v_lds[j][d] = v_t[(size_t)h * 6400 + idx];
  }
  __syncthreads();
  if (t < 200) {
    int ib = (t / 25) * 2, jb = (t % 25) * 4;
    const float* qp = q + h * 64 * NP + i0 + ib;
    const float* kp = k + h * 64 * 100 + jb;
    float a[2][4];
#pragma unroll
    for (int ii = 0; ii < 2; ++ii)
#pragma unroll
      for (int jj = 0; jj < 4; ++jj) a[ii][jj] = 0.f;
#pragma unroll 8
    for (int d = 0; d < 64; ++d) {
      f32x2 qv = *(const f32x2*)(qp + d * NP);
      f32x4 kv4 = *(const f32x4*)(kp + d * 100);
#pragma unroll
      for (int ii = 0; ii < 2; ++ii)
#pragma unroll
        for (int jj = 0; jj < 4; ++jj)
          a[ii][jj] = fmaf(qv[ii], kv4[jj], a[ii][jj]);
    }
    const float* bcol = bias_t + (size_t)h * 100 * 1600;
#pragma unroll
    for (int jj = 0; jj < 4; ++jj) {
      f32x2 bv = *(const f32x2*)(bcol + (size_t)(jb + jj) * 1600 + i0 + ib);
#pragma unroll
      for (int ii = 0; ii < 2; ++ii)
        s_lds[ib + ii][jb + jj] = fmaf(a[ii][jj], 0.125f, bv[ii]);
    }
  }
  __syncthreads();
  {
    int i = t >> 4, sub = t & 15;
    float m = -1e30f;
    for (int j = sub; j < 100; j += 16) m = fmaxf(m, s_lds[i][j]);
#pragma unroll
    for (int off = 1; off < 16; off <<= 1) m = fmaxf(m, __shfl_xor(m, off));
    float sum = 0.f;
    for (int j = sub; j < 100; j += 16) {
      float e = expf(s_lds[i][j] - m);
      s_lds[i][j] = e;
      sum += e;
    }
#pragma unroll
    for (int off = 1; off < 16; off <<= 1) sum += __shfl_xor(sum, off);
    float inv = 1.f / sum;
    for (int j = sub; j < 100; j += 16) s_lds[i][j] *= inv;
  }
  __syncthreads();
  {
    int i = t & 15, db = (t >> 4) * 4;
    float acc[4];
#pragma unroll
    for (int dd = 0; dd < 4; ++dd) acc[dd] = 0.f;
    for (int jc = 0; jc < 25; ++jc) {
      f32x4 sv = *(const f32x4*)&s_lds[i][jc * 4];
#pragma unroll
      for (int jj = 0; jj < 4; ++jj) {
        f32x4 vv = *(const f32x4*)&v_lds[jc * 4 + jj][db];
#pragma unroll
        for (int dd = 0; dd < 4; ++dd)
          acc[dd] = fmaf(sv[jj], vv[dd], acc[dd]);
      }
    }
#pragma unroll
    for (int dd = 0; dd < 4; ++dd)
      inner[(h * 64 + db + dd) * NP + i0 + i] = acc[dd];
  }
}

__global__ __launch_bounds__(256) void k_proj(
    const float* __restrict__ inner, const float* __restrict__ w,
    const float* __restrict__ bo, float* __restrict__ out) {
  int ot = blockIdx.x / 25;
  int pt = blockIdx.x - ot * 25;
  int t = threadIdx.x;
  int quad = __builtin_amdgcn_readfirstlane(t >> 6);
  int o0 = ot * 16 + quad * 4;
  int p = pt * 64 + (t & 63);
  const float* w0r = w + o0 * 512;
  float a0 = 0.f, a1 = 0.f, a2 = 0.f, a3 = 0.f;
#pragma unroll 8
  for (int c = 0; c < 512; ++c) {
    float xv = inner[c * NP + p];
    a0 = fmaf(w0r[c], xv, a0);
    a1 = fmaf(w0r[512 + c], xv, a1);
    a2 = fmaf(w0r[1024 + c], xv, a2);
    a3 = fmaf(w0r[1536 + c], xv, a3);
  }
  out[(o0 + 0) * NP + p] = a0 + bo[o0 + 0];
  out[(o0 + 1) * NP + p] = a1 + bo[o0 + 1];
  out[(o0 + 2) * NP + p] = a2 + bo[o0 + 2];
  out[(o0 + 3) * NP + p] = a3 + bo[o0 + 3];
}

extern "C" void kernel_launch(void* const* d_in, const int* in_sizes, int n_in,
                              void* d_out, int out_size, void* d_ws, size_t ws_size,
                              hipStream_t stream) {
  int L = in_sizes[1] / (512 * 32);
  int l = L - 1;
  const float* x      = (const float*)d_in[0];
  const float* wq     = (const float*)d_in[1]  + (size_t)l * 512 * 32;
  const float* wk     = (const float*)d_in[2]  + (size_t)l * 512 * 32;
  const float* wv     = (const float*)d_in[3]  + (size_t)l * 512 * 32;
  const float* w_off1 = (const float*)d_in[4]  + (size_t)l * 64 * 36;
  const float* b_off1 = (const float*)d_in[5]  + (size_t)l * 64;
  const float* w_off2 = (const float*)d_in[6]  + (size_t)l * 2 * 64;
  const float* cpb_w0 = (const float*)d_in[7]  + (size_t)l * 64 * 2;
  const float* cpb_b0 = (const float*)d_in[8]  + (size_t)l * 64;
  const float* cpb_w1 = (const float*)d_in[9]  + (size_t)l * 64 * 64;
  const float* cpb_b1 = (const float*)d_in[10] + (size_t)l * 64;
  const float* cpb_w2 = (const float*)d_in[11] + (size_t)l * 64;
  const float* cpb_b2 = (const float*)d_in[12] + (size_t)l * 1;
  const float* w_out  = (const float*)d_in[13] + (size_t)l * 256 * 512;
  const float* b_out  = (const float*)d_in[14] + (size_t)l * 256;
  float* out = (float*)d_out;

  float* ws = (float*)d_ws;
  float* q_ws    = ws;               // 819200 (fallback only)
  float* qt_ws   = ws + 819200;      // 819200 (transposed [p][512])
  float* k_ws    = ws + 1638400;     // 51200
  float* vt_ws   = ws + 1689600;     // 51200 (transposed [gj][c])
  float* bias_t  = ws + 1740800;     // 1280000 (transposed [gj][i])
  float* inner   = ws + 3020800;     // 819200  (end 3,840,000 f = 15.36 MB)

  void* args[] = {
    (void*)&x, (void*)&wq, (void*)&w_off1, (void*)&b_off1, (void*)&w_off2,
    (void*)&wk, (void*)&wv, (void*)&cpb_w0, (void*)&cpb_b0, (void*)&cpb_w1,
    (void*)&cpb_b1, (void*)&cpb_w2, (void*)&cpb_b2, (void*)&w_out, (void*)&b_out,
    (void*)&qt_ws, (void*)&k_ws, (void*)&vt_ws, (void*)&bias_t, (void*)&inner,
    (void*)&out
  };
  hipError_t err = hipLaunchCooperativeKernel((void*)k_fused, dim3(512),
                                              dim3(256), args, 0, stream);
  if (err != hipSuccess) {
    (void)hipGetLastError();   // clear sticky error, run proven 4-kernel path
    k_conv1x1<<<320, 256, 0, stream>>>(x, wq, q_ws, qt_ws);
    k_off_cpb<<<800, 256, 0, stream>>>(qt_ws, w_off1, b_off1, w_off2, x, wk, wv,
                                       cpb_w0, cpb_b0, cpb_w1, cpb_b1, cpb_w2,
                                       cpb_b2, k_ws, vt_ws, bias_t);
    k_attn<<<800, 256, 0, stream>>>(q_ws, k_ws, vt_ws, bias_t, inner);
    k_proj<<<400, 256, 0, stream>>>(inner, w_out, b_out, out);
  }
}